// Round 9
// baseline (102.960 us; speedup 1.0000x reference)
//
#include <hip/hip_runtime.h>
#include <math.h>

// WignerDRotation: out = Z(alpha) * J * Z(beta) * J * Z(gamma) * x, block-diagonal
// over irreps [0]*256 + [1]*256 + [2]*128 + [3]*64, DIM=2112, CH=32, N=1024.
// All copies of the same l share one d x d composite matrix M_l per batch row.
//
// Round-9 structure: ZERO barriers, ZERO LDS — waves fully independent, i.e.
// maximally copy-shaped. Each WAVE redundantly computes M: lane q (q<d, clamped
// for q>=d, no EXEC divergence) computes column q of M in registers while the
// unit's NT load burst is in flight; v_readlane (compile-time lane index)
// broadcasts all d^2 entries to SGPRs; FMAs keep the one-SGPR-operand form.
// Keeps rounds 5-8 winners: burst issue (8-14 vmem clusters), SGPR-M FMAs,
// sliding-window grid-stride over 6144 memory-ordered units, 1025 resident
// blocks, single fused kernel, __launch_bounds__(256,4).

namespace {

typedef float f4 __attribute__((ext_vector_type(4)));

constexpr float SQ3_2 = 0.86602540378443864676f;  // sqrt(3)/2
constexpr float S6    = 0.61237243569579452455f;  // sqrt(6)/4
constexpr float S10   = 0.79056941504209483300f;  // sqrt(10)/4
constexpr float S15   = 0.96824583655185422129f;  // sqrt(15)/4

// J_l: real-SH matrix of the y<->z axis swap (Condon-Shortley phase, rows/cols
// ordered m = -l..l). J = J^T = J^-1.
template<int L> struct JM;
template<> struct JM<1> {
  static constexpr float v[3][3] = {
    { 0.f, -1.f, 0.f},
    {-1.f,  0.f, 0.f},
    { 0.f,  0.f, 1.f}};
};
template<> struct JM<2> {
  static constexpr float v[5][5] = {
    { 0.f, 0.f,  0.f,   -1.f,  0.f},
    { 0.f, 1.f,  0.f,    0.f,  0.f},
    { 0.f, 0.f, -0.5f,   0.f, -SQ3_2},
    {-1.f, 0.f,  0.f,    0.f,  0.f},
    { 0.f, 0.f, -SQ3_2,  0.f,  0.5f}};
};
template<> struct JM<3> {
  static constexpr float v[7][7] = {
    { 0.f, 0.f, 0.f, S10,  0.f,   -S6,  0.f},
    { 0.f, 1.f, 0.f, 0.f,  0.f,    0.f, 0.f},
    { 0.f, 0.f, 0.f, S6,   0.f,    S10, 0.f},
    { S10, 0.f, S6,  0.f,  0.f,    0.f, 0.f},
    { 0.f, 0.f, 0.f, 0.f, -0.25f,  0.f, -S15},
    {-S6,  0.f, S10, 0.f,  0.f,    0.f, 0.f},
    { 0.f, 0.f, 0.f, 0.f, -S15,    0.f, 0.25f}};
};

// Column q of M_l = Zalpha * J * Zbeta * J * Zgamma, entirely in registers.
// Column-local: Z only mixes m <-> -m within a column; J*col is one sparse
// mat-vec of compile-time constants.
template<int L>
__device__ inline void compute_M_col_reg(int q, float al, float be, float ga,
                                         float* __restrict__ col) {
  constexpr int D = 2 * L + 1;
  const int mq = q - L;
  float sg, cg;
  __sincosf((float)mq * ga, &sg, &cg);
  float v[D];
#pragma unroll
  for (int p = 0; p < D; ++p) {
    // Runtime-q index into compile-time J: small D, compiler emits selects.
    float jq = 0.f, jr = 0.f;
#pragma unroll
    for (int c = 0; c < D; ++c) {
      jq = (c == q) ? JM<L>::v[p][c] : jq;
      jr = (c == (D - 1) - q) ? JM<L>::v[p][c] : jr;
    }
    v[p] = cg * jq + sg * jr;
  }
  float c1, s1;
  __sincosf(be, &s1, &c1);
  float cb[L + 1], sb[L + 1];
  cb[0] = 1.f; sb[0] = 0.f;
  cb[1] = c1;  sb[1] = s1;
#pragma unroll
  for (int k = 2; k <= L; ++k) {  // Chebyshev: cos/sin of k*beta
    cb[k] = 2.f * c1 * cb[k - 1] - cb[k - 2];
    sb[k] = 2.f * c1 * sb[k - 1] - sb[k - 2];
  }
  float w[D];
#pragma unroll
  for (int p = 0; p < D; ++p) {
    const int mp = p - L;
    const int am = mp < 0 ? -mp : mp;
    const float c = cb[am];
    const float s = mp < 0 ? -sb[am] : sb[am];
    w[p] = c * v[p] - s * v[(D - 1) - p];
  }
  float u[D];
#pragma unroll
  for (int p = 0; p < D; ++p) {
    float acc = 0.f;
#pragma unroll
    for (int r = 0; r < D; ++r) acc = fmaf(JM<L>::v[p][r], w[r], acc);
    u[p] = acc;
  }
  __sincosf(al, &s1, &c1);
  float ca[L + 1], sa[L + 1];
  ca[0] = 1.f; sa[0] = 0.f;
  ca[1] = c1;  sa[1] = s1;
#pragma unroll
  for (int k = 2; k <= L; ++k) {
    ca[k] = 2.f * c1 * ca[k - 1] - ca[k - 2];
    sa[k] = 2.f * c1 * sa[k - 1] - sa[k - 2];
  }
#pragma unroll
  for (int p = 0; p < D; ++p) {
    const int mp = p - L;
    const int am = mp < 0 ? -mp : mp;
    const float c = ca[am];
    const float s = mp < 0 ? -sa[am] : sa[am];
    col[p] = c * u[p] - s * u[(D - 1) - p];
  }
}

// Non-copy unit: group g (of 32) owns NC consecutive copies of dim D.
// Pipeline: NT load burst -> per-wave M columns in registers (hidden under HBM
// latency) -> readlane broadcast to SGPRs -> FMAs -> NT store burst.
template<int L, int NC>
__device__ inline void run_unit(const f4* __restrict__ inU,
                                f4* __restrict__ outU,
                                float al, float be, float ga,
                                int g, int ch, int lane) {
  constexpr int D = 2 * L + 1;
  const int base = g * (NC * D * 8) + ch;
  f4 v[NC][D];
#pragma unroll
  for (int j = 0; j < NC; ++j)
#pragma unroll
    for (int q = 0; q < D; ++q)
      v[j][q] = __builtin_nontemporal_load(inU + base + (j * D + q) * 8);

  // Lane q (clamped) computes column q of M; all lanes run the same code.
  const int q = lane < D ? lane : 0;
  float colv[D];
  compute_M_col_reg<L>(q, al, be, ga, colv);
  float Ms[D * D];
#pragma unroll
  for (int p = 0; p < D; ++p)
#pragma unroll
    for (int qq = 0; qq < D; ++qq)
      Ms[p * D + qq] = __int_as_float(
          __builtin_amdgcn_readlane(__float_as_int(colv[p]), qq));

  f4 o[NC][D];
#pragma unroll
  for (int j = 0; j < NC; ++j)
#pragma unroll
    for (int p = 0; p < D; ++p) {
      f4 a = Ms[p * D] * v[j][0];
#pragma unroll
      for (int qq = 1; qq < D; ++qq) a += Ms[p * D + qq] * v[j][qq];
      o[j][p] = a;
    }
#pragma unroll
  for (int j = 0; j < NC; ++j)
#pragma unroll
    for (int p = 0; p < D; ++p)
      __builtin_nontemporal_store(o[j][p], outU + base + (j * D + p) * 8);
}

// Unit table per n (f4 offsets, 16896 f4 per row), 6 units/n, address-ordered:
//  k=0: l0 copy @0 (2048 f4)           k=1,2: l1 128 copies @2048+3072(k-1)
//  k=3,4: l2 64 copies @8192+2560(k-3) k=5: l3 64 copies @13312 (3584 f4)
// Grid stride 1025 (= 5 mod 6): each block cycles all unit types (balanced),
// unit order == memory order (sliding contiguous window over the 554 MB).
__global__ __launch_bounds__(256, 4) void wigner_kernel(
    const float* __restrict__ in, const float* __restrict__ alpha,
    const float* __restrict__ beta, const float* __restrict__ gamma,
    float* __restrict__ out, int n_units, int grid) {
  const int t = threadIdx.x;
  const int g = t >> 3, ch = t & 7, lane = t & 63;
  for (int u = blockIdx.x; u < n_units; u += grid) {
    const int n = u / 6, k = u - n * 6;
    const size_t base = (size_t)n * 16896;
    const f4* inN = (const f4*)in + base;
    f4* outN = (f4*)out + base;
    if (k == 0) {
      f4 c[8];
#pragma unroll
      for (int j = 0; j < 8; ++j)
        c[j] = __builtin_nontemporal_load(inN + t + 256 * j);
#pragma unroll
      for (int j = 0; j < 8; ++j)
        __builtin_nontemporal_store(c[j], outN + t + 256 * j);
    } else {
      const float al = alpha[n], be = beta[n], ga = gamma[n];
      if (k <= 2) {
        const int soff = 2048 + (k - 1) * 3072;
        run_unit<1, 4>(inN + soff, outN + soff, al, be, ga, g, ch, lane);
      } else if (k <= 4) {
        const int soff = 8192 + (k - 3) * 2560;
        run_unit<2, 2>(inN + soff, outN + soff, al, be, ga, g, ch, lane);
      } else {
        run_unit<3, 2>(inN + 13312, outN + 13312, al, be, ga, g, ch, lane);
      }
    }
  }
}

}  // namespace

extern "C" void kernel_launch(void* const* d_in, const int* in_sizes, int n_in,
                              void* d_out, int out_size, void* d_ws, size_t ws_size,
                              hipStream_t stream) {
  const float* in    = (const float*)d_in[0];
  const float* alpha = (const float*)d_in[1];
  const float* beta  = (const float*)d_in[2];
  const float* gamma = (const float*)d_in[3];
  float* out = (float*)d_out;
  const int n_batch = in_sizes[1];  // 1024

  const int n_units = n_batch * 6;
  const int grid = n_units < 1025 ? n_units : 1025;  // ~all-resident, 5 mod 6
  wigner_kernel<<<grid, 256, 0, stream>>>(in, alpha, beta, gamma, out,
                                          n_units, grid);
}